// Round 2
// baseline (523.017 us; speedup 1.0000x reference)
//
#include <hip/hip_runtime.h>
#include <math.h>

static constexpr int BB  = 64;
static constexpr int DIN = 5000;
static constexpr int NHID = 1000;
static constexpr int NG  = 512;
static constexpr int NK  = 8;
static constexpr int NM  = 32;
static constexpr int GS  = 512;
static constexpr int NC  = NK * GS;  // 4096
static constexpr int NPAIR = BB * NK;  // 512

// split-K GEMM configs
static constexpr int S1 = 16, CHD1 = 320, IT1 = 16, IP1 = 1024;
static constexpr int S2 = 16, CHD2 = 64,  IT2 = 8,  IP2 = 512;

// part[s][b][i] = sum_{d in chunk s} A[b,d] * Bm[i,d]
__global__ __launch_bounds__(256) void gemm64(
    const float* __restrict__ A, int lda,
    const float* __restrict__ Bm, int ldb, int Ireal,
    float* __restrict__ part, int Ipad, int Itiles, int D, int CHD)
{
  __shared__ __align__(16) float xT[32][64];
  __shared__ __align__(16) float wT[32][64];
  const int tid = threadIdx.x;
  const int itile = blockIdx.x % Itiles;
  const int s = blockIdx.x / Itiles;
  const int d_beg = s * CHD;
  const int d_end = min(D, d_beg + CHD);
  const int tx = tid & 15;   // b dimension (b0 = 4*tx)
  const int ty = tid >> 4;   // i dimension (i0 = 4*ty)
  float acc[4][4] = {};

  for (int d0 = d_beg; d0 < d_end; d0 += 32) {
#pragma unroll
    for (int q = 0; q < 2; q++) {
      int lin = q * 256 + tid;
      int r = lin >> 3;
      int c4 = (lin & 7) << 2;
      int d = d0 + c4;
      const float* pr = A + (size_t)r * lda;
      float4 v = make_float4(0.f, 0.f, 0.f, 0.f);
      if (d + 4 <= d_end) v = *(const float4*)(pr + d);
      else {
        if (d + 0 < d_end) v.x = pr[d + 0];
        if (d + 1 < d_end) v.y = pr[d + 1];
        if (d + 2 < d_end) v.z = pr[d + 2];
        if (d + 3 < d_end) v.w = pr[d + 3];
      }
      xT[c4 + 0][r] = v.x; xT[c4 + 1][r] = v.y;
      xT[c4 + 2][r] = v.z; xT[c4 + 3][r] = v.w;
    }
#pragma unroll
    for (int q = 0; q < 2; q++) {
      int lin = q * 256 + tid;
      int r = lin >> 3;
      int c4 = (lin & 7) << 2;
      int ib = itile * 64 + r;
      int d = d0 + c4;
      float4 v = make_float4(0.f, 0.f, 0.f, 0.f);
      if (ib < Ireal) {
        const float* pr = Bm + (size_t)ib * ldb;
        if (d + 4 <= d_end) v = *(const float4*)(pr + d);
        else {
          if (d + 0 < d_end) v.x = pr[d + 0];
          if (d + 1 < d_end) v.y = pr[d + 1];
          if (d + 2 < d_end) v.z = pr[d + 2];
          if (d + 3 < d_end) v.w = pr[d + 3];
        }
      }
      wT[c4 + 0][r] = v.x; wT[c4 + 1][r] = v.y;
      wT[c4 + 2][r] = v.z; wT[c4 + 3][r] = v.w;
    }
    __syncthreads();
    const int nn = min(32, d_end - d0);
    if (nn == 32) {
#pragma unroll
      for (int dd = 0; dd < 32; dd++) {
        float4 xv = *(const float4*)&xT[dd][tx << 2];
        float4 wv = *(const float4*)&wT[dd][ty << 2];
        float xr[4] = {xv.x, xv.y, xv.z, xv.w};
        float wr[4] = {wv.x, wv.y, wv.z, wv.w};
#pragma unroll
        for (int a = 0; a < 4; a++)
#pragma unroll
          for (int c = 0; c < 4; c++)
            acc[a][c] = fmaf(xr[a], wr[c], acc[a][c]);
      }
    } else {
      for (int dd = 0; dd < nn; dd++) {
        float4 xv = *(const float4*)&xT[dd][tx << 2];
        float4 wv = *(const float4*)&wT[dd][ty << 2];
        float xr[4] = {xv.x, xv.y, xv.z, xv.w};
        float wr[4] = {wv.x, wv.y, wv.z, wv.w};
#pragma unroll
        for (int a = 0; a < 4; a++)
#pragma unroll
          for (int c = 0; c < 4; c++)
            acc[a][c] = fmaf(xr[a], wr[c], acc[a][c]);
      }
    }
    __syncthreads();
  }

  const int b0 = tx << 2;
  const int i0 = itile * 64 + (ty << 2);
#pragma unroll
  for (int a = 0; a < 4; a++) {
    float4 vv = make_float4(acc[a][0], acc[a][1], acc[a][2], acc[a][3]);
    *(float4*)&part[((size_t)s * BB + (b0 + a)) * Ipad + i0] = vv;
  }
}

__global__ void reduce_act(const float* __restrict__ part, int S, int Ipad, int Ireal,
                           const float* __restrict__ bias, float* __restrict__ out,
                           int ostride, int mode)
{
  int lin = blockIdx.x * blockDim.x + threadIdx.x;
  int n = BB * Ireal;
  if (lin >= n) return;
  int b = lin / Ireal;
  int i = lin - b * Ireal;
  float sum = bias[i];
  for (int s = 0; s < S; s++) sum += part[((size_t)s * BB + b) * Ipad + i];
  if (mode == 0) sum = fmaxf(sum, 0.f);
  else           sum = 1.f / (1.f + expf(-sum));
  out[(size_t)b * ostride + i] = sum;
}

// per-sample top-8 (descending, tie -> lower index) + fused BCE term2
__global__ __launch_bounds__(64) void topk_loss2(
    const float* __restrict__ y, const float* __restrict__ gl,
    int* __restrict__ idxo, float* __restrict__ acc)
{
  const int b = blockIdx.x;
  const int lane = threadIdx.x;
  float v[8];
  float l2 = 0.f;
#pragma unroll
  for (int j = 0; j < 8; j++) {
    int pos = j * 64 + lane;
    float z = y[b * NG + pos];
    v[j] = z;
    float t = gl[b * NG + pos];
    l2 += fmaxf(z, 0.f) + log1pf(expf(-fabsf(z))) - z * t;
  }
  for (int k = 0; k < 8; k++) {
    float bv = -INFINITY;
    int bi = 0x7fffffff;
#pragma unroll
    for (int j = 0; j < 8; j++) {
      int pos = j * 64 + lane;
      if (v[j] > bv) { bv = v[j]; bi = pos; }
    }
#pragma unroll
    for (int off = 32; off >= 1; off >>= 1) {
      float ov = __shfl_xor(bv, off, 64);
      int   oi = __shfl_xor(bi, off, 64);
      if (ov > bv || (ov == bv && oi < bi)) { bv = ov; bi = oi; }
    }
    if (lane == 0) idxo[b * NK + k] = bi;
    if (lane == (bi & 63)) {
      int jj = bi >> 6;
#pragma unroll
      for (int j = 0; j < 8; j++) if (j == jj) v[j] = -INFINITY;
    }
  }
#pragma unroll
  for (int off = 32; off >= 1; off >>= 1) l2 += __shfl_xor(l2, off, 64);
  if (lane == 0) atomicAdd(acc + 1, l2);
}

// dedupe the 512 (b,k) group selections: unique-by-first-occurrence,
// pair lists per unique group. One block, fully deterministic.
__global__ __launch_bounds__(512) void prep_groups(
    const int* __restrict__ idxb, int* __restrict__ ug, int* __restrict__ ucnt,
    int* __restrict__ upairs, int* __restrict__ ucountp)
{
  __shared__ int gs[NPAIR];
  __shared__ int fs[NPAIR];
  const int i = threadIdx.x;
  gs[i] = idxb[i];
  __syncthreads();
  const int g = gs[i];
  int first = i, rank = 0, cnt = 0;
  for (int j = 0; j < NPAIR; j++) {
    int gj = gs[j];
    if (gj == g) { cnt++; if (j < first) first = j; if (j < i) rank++; }
  }
  fs[i] = first;
  __syncthreads();
  int uid = 0;
  for (int j = 0; j < first; j++) uid += (fs[j] == j);
  if (first == i) { ug[uid] = g; ucnt[uid] = cnt; }
  upairs[uid * 64 + rank] = i;
  if (i == 0) {
    int total = 0;
    for (int j = 0; j < NPAIR; j++) total += (fs[j] == j);
    *ucountp = total;
  }
}

// group-major scoring: block j handles unique group j; reads each emb row
// once from HBM, dots against all P selecting samples' y (<=8 staged in LDS
// per pass; extra passes re-read emb from hot L2).
__global__ __launch_bounds__(512) void score2(
    const float* __restrict__ emb, const float* __restrict__ y,
    const int* __restrict__ ug, const int* __restrict__ ucnt,
    const int* __restrict__ upairs, const int* __restrict__ ucountp,
    const int* __restrict__ cands, const float* __restrict__ labels,
    const int* __restrict__ group_y, float* __restrict__ out,
    float* __restrict__ acc)
{
  const int j = blockIdx.x;
  if (j >= *ucountp) return;
  const int g = ug[j];
  const int P = ucnt[j];
  __shared__ int cid[GS];
  __shared__ int plist[64];
  __shared__ __align__(16) float yl[8][NG];  // 16 KB
  __shared__ int tgtc[8][NM];
  __shared__ float red[8];
  const int tid = threadIdx.x;
  cid[tid] = group_y[g * GS + tid];
  if (tid < P) plist[tid] = upairs[j * 64 + tid];

  const int l = tid & 15;
  const int grp = tid >> 4;  // 0..31
  float lossp = 0.f;

  for (int c0 = 0; c0 < P; c0 += 8) {
    const int pc = min(8, P - c0);
    __syncthreads();  // previous pass reads done (and cid/plist visible)
    {
      int p = tid >> 6;       // 0..7
      int e = (tid & 63) * 8; // 8 floats per thread
      if (p < pc) {
        int b = plist[c0 + p] >> 3;
        const float4* src = (const float4*)(y + (size_t)b * NG + e);
        float4* dst = (float4*)&yl[p][e];
        dst[0] = src[0]; dst[1] = src[1];
      }
      if (tid < pc * NM) {
        int pp = tid >> 5, m = tid & 31;
        int b = plist[c0 + pp] >> 3;
        tgtc[pp][m] = labels[b * NM + m] > 0.5f ? cands[b * NM + m] : -1;
      }
    }
    __syncthreads();

    for (int it = 0; it < 16; it++) {
      int row = it * 32 + grp;
      int r = cid[row];
      const float4* ep = (const float4*)(emb + (size_t)r * NG);
      float4 e[8];
#pragma unroll
      for (int seg = 0; seg < 8; seg++) e[seg] = ep[seg * 16 + l];
      for (int p = 0; p < pc; p++) {
        const float4* yp4 = (const float4*)yl[p];
        float sum = 0.f;
#pragma unroll
        for (int seg = 0; seg < 8; seg++) {
          float4 yv = yp4[seg * 16 + l];
          sum = fmaf(e[seg].x, yv.x, sum);
          sum = fmaf(e[seg].y, yv.y, sum);
          sum = fmaf(e[seg].z, yv.z, sum);
          sum = fmaf(e[seg].w, yv.w, sum);
        }
        sum += __shfl_xor(sum, 1, 64);
        sum += __shfl_xor(sum, 2, 64);
        sum += __shfl_xor(sum, 4, 64);
        sum += __shfl_xor(sum, 8, 64);
        if (l == 0) {
          int pair = plist[c0 + p];
          out[(size_t)pair * GS + row] = sum;
          float nl = 0.f;
#pragma unroll
          for (int m = 0; m < NM; m++) if (r == tgtc[p][m]) nl = 1.f;
          lossp += fmaxf(sum, 0.f) + log1pf(expf(-fabsf(sum))) - sum * nl;
        }
      }
    }
  }

#pragma unroll
  for (int off = 32; off >= 1; off >>= 1) lossp += __shfl_xor(lossp, off, 64);
  const int wid = tid >> 6;
  if ((tid & 63) == 0) red[wid] = lossp;
  __syncthreads();
  if (tid == 0) {
    float t = 0.f;
#pragma unroll
    for (int w = 0; w < 8; w++) t += red[w];
    atomicAdd(acc, t);
  }
}

__global__ void finalize_loss(const float* __restrict__ acc, float* __restrict__ out)
{
  out[(size_t)BB * NC] = acc[0] * (1.f / (float)(BB * NC)) +
                         acc[1] * (1.f / (float)(BB * NG));
}

extern "C" void kernel_launch(void* const* d_in, const int* in_sizes, int n_in,
                              void* d_out, int out_size, void* d_ws, size_t ws_size,
                              hipStream_t stream)
{
  const float* x      = (const float*)d_in[0];
  const int*   cands  = (const int*)  d_in[1];
  const float* labels = (const float*)d_in[2];
  const float* glab   = (const float*)d_in[3];
  const float* W1     = (const float*)d_in[4];
  const float* b1     = (const float*)d_in[5];
  const float* W2     = (const float*)d_in[6];
  const float* b2     = (const float*)d_in[7];
  const float* emb    = (const float*)d_in[8];
  const int*   gy     = (const int*)  d_in[9];
  float* out = (float*)d_out;

  // ws layout (floats): acc[16] | y[64*512] | idx[512] | h[64*1024] |
  // p1[16*64*1024] | p2[16*64*512] | ug[512] | ucnt[512] | ucount[16] |
  // upairs[512*64]   (~6.9 MB)
  float* ws   = (float*)d_ws;
  float* acc  = ws;
  float* y    = ws + 16;
  int*   idxb = (int*)(y + BB * NG);
  float* h    = (float*)(idxb + NPAIR);
  float* p1   = h + (size_t)BB * IP1;
  float* p2   = p1 + (size_t)S1 * BB * IP1;
  int*   ug   = (int*)(p2 + (size_t)S2 * BB * IP2);
  int*   ucnt = ug + NPAIR;
  int*   ucountp = ucnt + NPAIR;
  int*   upairs  = ucountp + 16;

  hipMemsetAsync(acc, 0, 2 * sizeof(float), stream);

  gemm64<<<IT1 * S1, 256, 0, stream>>>(x, DIN, W1, DIN, NHID, p1, IP1, IT1, DIN, CHD1);
  reduce_act<<<(BB * NHID + 255) / 256, 256, 0, stream>>>(p1, S1, IP1, NHID, b1, h, IP1, 0);

  gemm64<<<IT2 * S2, 256, 0, stream>>>(h, IP1, W2, NHID, NG, p2, IP2, IT2, NHID, CHD2);
  reduce_act<<<(BB * NG + 255) / 256, 256, 0, stream>>>(p2, S2, IP2, NG, b2, y, NG, 1);

  topk_loss2<<<BB, 64, 0, stream>>>(y, glab, idxb, acc);

  prep_groups<<<1, NPAIR, 0, stream>>>(idxb, ug, ucnt, upairs, ucountp);

  score2<<<NPAIR, 512, 0, stream>>>(emb, y, ug, ucnt, upairs, ucountp,
                                    cands, labels, gy, out, acc);

  finalize_loss<<<1, 1, 0, stream>>>(acc, out);
}

// Round 3
// 124.750 us; speedup vs baseline: 4.1925x; 4.1925x over previous
//
#include <hip/hip_runtime.h>
#include <math.h>

static constexpr int BB  = 64;
static constexpr int DIN = 5000;
static constexpr int NHID = 1000;
static constexpr int NG  = 512;
static constexpr int NK  = 8;
static constexpr int NM  = 32;
static constexpr int GS  = 512;
static constexpr int NC  = NK * GS;   // 4096
static constexpr int NPAIR = BB * NK; // 512

// split-K GEMM configs
static constexpr int S1 = 16, CHD1 = 320, IT1 = 16, IP1 = 1024;
static constexpr int S2 = 16, CHD2 = 64,  IT2 = 8,  IP2 = 512;

// part[s][b][i] = sum_{d in chunk s} A[b,d] * Bm[i,d]
__global__ __launch_bounds__(256) void gemm64(
    const float* __restrict__ A, int lda,
    const float* __restrict__ Bm, int ldb, int Ireal,
    float* __restrict__ part, int Ipad, int Itiles, int D, int CHD)
{
  __shared__ __align__(16) float xT[32][64];
  __shared__ __align__(16) float wT[32][64];
  const int tid = threadIdx.x;
  const int itile = blockIdx.x % Itiles;
  const int s = blockIdx.x / Itiles;
  const int d_beg = s * CHD;
  const int d_end = min(D, d_beg + CHD);
  const int tx = tid & 15;
  const int ty = tid >> 4;
  float acc[4][4] = {};

  for (int d0 = d_beg; d0 < d_end; d0 += 32) {
#pragma unroll
    for (int q = 0; q < 2; q++) {
      int lin = q * 256 + tid;
      int r = lin >> 3;
      int c4 = (lin & 7) << 2;
      int d = d0 + c4;
      const float* pr = A + (size_t)r * lda;
      float4 v = make_float4(0.f, 0.f, 0.f, 0.f);
      if (d + 4 <= d_end) v = *(const float4*)(pr + d);
      else {
        if (d + 0 < d_end) v.x = pr[d + 0];
        if (d + 1 < d_end) v.y = pr[d + 1];
        if (d + 2 < d_end) v.z = pr[d + 2];
        if (d + 3 < d_end) v.w = pr[d + 3];
      }
      xT[c4 + 0][r] = v.x; xT[c4 + 1][r] = v.y;
      xT[c4 + 2][r] = v.z; xT[c4 + 3][r] = v.w;
    }
#pragma unroll
    for (int q = 0; q < 2; q++) {
      int lin = q * 256 + tid;
      int r = lin >> 3;
      int c4 = (lin & 7) << 2;
      int ib = itile * 64 + r;
      int d = d0 + c4;
      float4 v = make_float4(0.f, 0.f, 0.f, 0.f);
      if (ib < Ireal) {
        const float* pr = Bm + (size_t)ib * ldb;
        if (d + 4 <= d_end) v = *(const float4*)(pr + d);
        else {
          if (d + 0 < d_end) v.x = pr[d + 0];
          if (d + 1 < d_end) v.y = pr[d + 1];
          if (d + 2 < d_end) v.z = pr[d + 2];
          if (d + 3 < d_end) v.w = pr[d + 3];
        }
      }
      wT[c4 + 0][r] = v.x; wT[c4 + 1][r] = v.y;
      wT[c4 + 2][r] = v.z; wT[c4 + 3][r] = v.w;
    }
    __syncthreads();
    const int nn = min(32, d_end - d0);
    if (nn == 32) {
#pragma unroll
      for (int dd = 0; dd < 32; dd++) {
        float4 xv = *(const float4*)&xT[dd][tx << 2];
        float4 wv = *(const float4*)&wT[dd][ty << 2];
        float xr[4] = {xv.x, xv.y, xv.z, xv.w};
        float wr[4] = {wv.x, wv.y, wv.z, wv.w};
#pragma unroll
        for (int a = 0; a < 4; a++)
#pragma unroll
          for (int c = 0; c < 4; c++)
            acc[a][c] = fmaf(xr[a], wr[c], acc[a][c]);
      }
    } else {
      for (int dd = 0; dd < nn; dd++) {
        float4 xv = *(const float4*)&xT[dd][tx << 2];
        float4 wv = *(const float4*)&wT[dd][ty << 2];
        float xr[4] = {xv.x, xv.y, xv.z, xv.w};
        float wr[4] = {wv.x, wv.y, wv.z, wv.w};
#pragma unroll
        for (int a = 0; a < 4; a++)
#pragma unroll
          for (int c = 0; c < 4; c++)
            acc[a][c] = fmaf(xr[a], wr[c], acc[a][c]);
      }
    }
    __syncthreads();
  }

  const int b0 = tx << 2;
  const int i0 = itile * 64 + (ty << 2);
#pragma unroll
  for (int a = 0; a < 4; a++) {
    float4 vv = make_float4(acc[a][0], acc[a][1], acc[a][2], acc[a][3]);
    *(float4*)&part[((size_t)s * BB + (b0 + a)) * Ipad + i0] = vv;
  }
}

__global__ void reduce_act(const float* __restrict__ part, int S, int Ipad, int Ireal,
                           const float* __restrict__ bias, float* __restrict__ out,
                           int ostride, int mode)
{
  int lin = blockIdx.x * blockDim.x + threadIdx.x;
  int n = BB * Ireal;
  if (lin >= n) return;
  int b = lin / Ireal;
  int i = lin - b * Ireal;
  float sum = bias[i];
  for (int s = 0; s < S; s++) sum += part[((size_t)s * BB + b) * Ipad + i];
  if (mode == 0) sum = fmaxf(sum, 0.f);
  else           sum = 1.f / (1.f + expf(-sum));
  out[(size_t)b * ostride + i] = sum;
}

// per-sample top-8 (descending, tie -> lower index) + fused BCE term2
__global__ __launch_bounds__(64) void topk_loss2(
    const float* __restrict__ y, const float* __restrict__ gl,
    int* __restrict__ idxo, float* __restrict__ acc)
{
  const int b = blockIdx.x;
  const int lane = threadIdx.x;
  float v[8];
  float l2 = 0.f;
#pragma unroll
  for (int j = 0; j < 8; j++) {
    int pos = j * 64 + lane;
    float z = y[b * NG + pos];
    v[j] = z;
    float t = gl[b * NG + pos];
    l2 += fmaxf(z, 0.f) + log1pf(expf(-fabsf(z))) - z * t;
  }
  for (int k = 0; k < 8; k++) {
    float bv = -INFINITY;
    int bi = 0x7fffffff;
#pragma unroll
    for (int j = 0; j < 8; j++) {
      int pos = j * 64 + lane;
      if (v[j] > bv) { bv = v[j]; bi = pos; }
    }
#pragma unroll
    for (int off = 32; off >= 1; off >>= 1) {
      float ov = __shfl_xor(bv, off, 64);
      int   oi = __shfl_xor(bi, off, 64);
      if (ov > bv || (ov == bv && oi < bi)) { bv = ov; bi = oi; }
    }
    if (lane == 0) idxo[b * NK + k] = bi;
    if (lane == (bi & 63)) {
      int jj = bi >> 6;
#pragma unroll
      for (int j = 0; j < 8; j++) if (j == jj) v[j] = -INFINITY;
    }
  }
#pragma unroll
  for (int off = 32; off >= 1; off >>= 1) l2 += __shfl_xor(l2, off, 64);
  if (lane == 0) atomicAdd(acc + 1, l2);
}

// deterministic sort of the 512 (b,k) pairs by (group id, pair index):
// order[rank] = pair. One block, O(512^2) LDS broadcasts (~few us).
__global__ __launch_bounds__(512) void sort_pairs(
    const int* __restrict__ idxb, int* __restrict__ order)
{
  __shared__ int gs[NPAIR];
  const int i = threadIdx.x;
  gs[i] = idxb[i];
  __syncthreads();
  const int g = gs[i];
  int pos = 0;
  for (int j = 0; j < NPAIR; j++) {
    int gj = gs[j];
    pos += (gj < g) || (gj == g && j < i);
  }
  order[pos] = i;
}

// streaming pair-major scoring, group-sorted + XCD-chunked ordering.
// 1024 blocks: logical index L = (blockIdx&7)*128 + blockIdx>>3;
// pair = order[L>>1], half = L&1 (rows half*256 .. half*256+255).
// Duplicate groups are adjacent in L and share an XCD -> L2/L3 hits.
__global__ __launch_bounds__(512) void score3(
    const float* __restrict__ emb, const float* __restrict__ y,
    const int* __restrict__ order, const int* __restrict__ idxb,
    const int* __restrict__ cands, const float* __restrict__ labels,
    const int* __restrict__ group_y, float* __restrict__ out,
    float* __restrict__ acc)
{
  const int L = (blockIdx.x & 7) * 128 + (blockIdx.x >> 3);
  const int pair = order[L >> 1];
  const int half = L & 1;
  const int b = pair >> 3;
  const int g = idxb[pair];
  __shared__ __align__(16) float yl[NG];
  __shared__ int cid[256];
  __shared__ int tgt[NM];
  __shared__ float red[8];
  const int tid = threadIdx.x;
  yl[tid] = y[b * NG + tid];
  if (tid < 256) cid[tid] = group_y[g * GS + half * 256 + tid];
  if (tid >= 256 && tid < 256 + NM) {
    int m = tid - 256;
    tgt[m] = labels[b * NM + m] > 0.5f ? cands[b * NM + m] : -1;
  }
  __syncthreads();

  const int l = tid & 15;
  const int grp = tid >> 4;  // 0..31
  const float4* yl4 = (const float4*)yl;
  float lossp = 0.f;

  for (int it = 0; it < 8; it++) {
    int rloc = it * 32 + grp;           // 0..255
    int row = half * 256 + rloc;        // 0..511
    int r = cid[rloc];
    const float4* ep = (const float4*)(emb + (size_t)r * NG);
    float sum = 0.f;
#pragma unroll
    for (int seg = 0; seg < 8; seg++) {
      float4 e  = ep[seg * 16 + l];
      float4 yv = yl4[seg * 16 + l];
      sum = fmaf(e.x, yv.x, sum);
      sum = fmaf(e.y, yv.y, sum);
      sum = fmaf(e.z, yv.z, sum);
      sum = fmaf(e.w, yv.w, sum);
    }
    sum += __shfl_xor(sum, 1, 64);
    sum += __shfl_xor(sum, 2, 64);
    sum += __shfl_xor(sum, 4, 64);
    sum += __shfl_xor(sum, 8, 64);
    if (l == 0) {
      out[(size_t)pair * GS + row] = sum;
      float nl = 0.f;
#pragma unroll
      for (int m = 0; m < NM; m++) if (r == tgt[m]) nl = 1.f;
      lossp += fmaxf(sum, 0.f) + log1pf(expf(-fabsf(sum))) - sum * nl;
    }
  }
#pragma unroll
  for (int off = 32; off >= 1; off >>= 1) lossp += __shfl_xor(lossp, off, 64);
  const int wid = tid >> 6;
  if ((tid & 63) == 0) red[wid] = lossp;
  __syncthreads();
  if (tid == 0) {
    float t = 0.f;
#pragma unroll
    for (int w = 0; w < 8; w++) t += red[w];
    atomicAdd(acc, t);
  }
}

__global__ void finalize_loss(const float* __restrict__ acc, float* __restrict__ out)
{
  out[(size_t)BB * NC] = acc[0] * (1.f / (float)(BB * NC)) +
                         acc[1] * (1.f / (float)(BB * NG));
}

extern "C" void kernel_launch(void* const* d_in, const int* in_sizes, int n_in,
                              void* d_out, int out_size, void* d_ws, size_t ws_size,
                              hipStream_t stream)
{
  const float* x      = (const float*)d_in[0];
  const int*   cands  = (const int*)  d_in[1];
  const float* labels = (const float*)d_in[2];
  const float* glab   = (const float*)d_in[3];
  const float* W1     = (const float*)d_in[4];
  const float* b1     = (const float*)d_in[5];
  const float* W2     = (const float*)d_in[6];
  const float* b2     = (const float*)d_in[7];
  const float* emb    = (const float*)d_in[8];
  const int*   gy     = (const int*)  d_in[9];
  float* out = (float*)d_out;

  // ws layout (floats): acc[16] | y[64*512] | idx[512] | h[64*1024] |
  // p1[16*64*1024] | p2[16*64*512] | order[512]
  float* ws   = (float*)d_ws;
  float* acc  = ws;
  float* y    = ws + 16;
  int*   idxb = (int*)(y + BB * NG);
  float* h    = (float*)(idxb + NPAIR);
  float* p1   = h + (size_t)BB * IP1;
  float* p2   = p1 + (size_t)S1 * BB * IP1;
  int*   order = (int*)(p2 + (size_t)S2 * BB * IP2);

  hipMemsetAsync(acc, 0, 2 * sizeof(float), stream);

  gemm64<<<IT1 * S1, 256, 0, stream>>>(x, DIN, W1, DIN, NHID, p1, IP1, IT1, DIN, CHD1);
  reduce_act<<<(BB * NHID + 255) / 256, 256, 0, stream>>>(p1, S1, IP1, NHID, b1, h, IP1, 0);

  gemm64<<<IT2 * S2, 256, 0, stream>>>(h, IP1, W2, NHID, NG, p2, IP2, IT2, NHID, CHD2);
  reduce_act<<<(BB * NG + 255) / 256, 256, 0, stream>>>(p2, S2, IP2, NG, b2, y, NG, 1);

  topk_loss2<<<BB, 64, 0, stream>>>(y, glab, idxb, acc);

  sort_pairs<<<1, NPAIR, 0, stream>>>(idxb, order);

  score3<<<2 * NPAIR, 512, 0, stream>>>(emb, y, order, idxb, cands, labels, gy, out, acc);

  finalize_loss<<<1, 1, 0, stream>>>(acc, out);
}